// Round 12
// baseline (166.624 us; speedup 1.0000x reference)
//
#include <hip/hip_runtime.h>
#include <math.h>

#define NVOX 50000
#define PPTS 32
#define HDIM 64
#define ODIM 128
#define EPSBN 1e-5f

typedef _Float16 f16x8 __attribute__((ext_vector_type(8)));
typedef _Float16 f16x4 __attribute__((ext_vector_type(4)));
typedef float f32x4 __attribute__((ext_vector_type(4)));

// d_ws layout (f16 elements unless noted):
//   [0, 512)       W1c: 64 rows x 8 f16  {w0..w3, c1, 0,0,0}   (BN-folded layer1)
//                  rows PERMUTED by perm(p) so phase-1 D output packs directly
//                  into phase-2 B fragments (in-register chaining, no LDS).
//   [512, 4608)    W2T: [row_phys][ch_in] 64x64, BN-folded; rows permuted by perm(p),
//                  columns natural (phase-1 pack delivers slot k = natural channel).
//   [4608, 12800)  W3T: [o][ch_in] 128x64 natural (phase-2 pack is identity too)
//   byte 25600:    f32 c2[64] natural, f32 b3[128]
#define WS_W1C 0
#define WS_W2T 512
#define WS_W3T 4608
#define WS_F32_BYTE 25600
#define FOLD_THREADS 12992

// Structure history:
//  - rounds 5-7: chunked persistent loops (rolled AND pragma-unrolled with
//    rotate arrays) demoted pipeline state to scratch (FETCH 450-750 MB).
//  - round 8: wave-uniform group skip: 77->69.5 us, VGPR 60, traffic ideal.
//  - round 10: (256,6) spilled (cap ~85 too tight). round 11: (256,4) neutral
//    -> occupancy is NOT cap-limited; it's block-churn limited (blocks live
//    ~2.8 us, serial startup dominates; both pipes <50% busy).
//  - this round: 2 chunks (4 voxels / 128 points) per wave, STRAIGHT-LINE
//    (macro-duplicated body, distinct named SSA locals, no rotate arrays —
//    the demotion-safe form). Grid 6250->3125; W3 staging + weight preloads
//    + barrier amortized 2x; chunk-1 vf/vnp loads issued up-front so they
//    fly during chunk-0 compute. launch_bounds stays (256,3) (cap 170 >>
//    expected ~90 live; rounds 3/10 proved wide margins are mandatory).

// Row permutation: physical MFMA-A row p (tile mt = p>>4, mu = p&15) holds
// logical channel 32*(mt&1) + 8*(mu>>2) + 4*(mt>>1) + (mu&3).
// Then lane(q,m16)'s D regs acc[mt][r] hold channels 32*(mt&1)+8q+4*(mt>>1)+r,
// and packing frag[kk=mt&1][j=4*(mt>>1)+r] puts channel c in B/A slot k = c.
__device__ __host__ inline int permch(int p) {
    return ((p >> 4) & 1) * 32 + ((p >> 2) & 3) * 8 + ((p >> 5) & 1) * 4 + (p & 3);
}

__global__ void vfe_fold(
    const float* __restrict__ W1, const float* __restrict__ b1,
    const float* __restrict__ g1, const float* __restrict__ be1,
    const float* __restrict__ m1, const float* __restrict__ v1,
    const float* __restrict__ W2, const float* __restrict__ b2,
    const float* __restrict__ g2, const float* __restrict__ be2,
    const float* __restrict__ m2, const float* __restrict__ v2,
    const float* __restrict__ W3, const float* __restrict__ b3,
    _Float16* __restrict__ wsh, float* __restrict__ wsf)
{
    int t = blockIdx.x * 256 + threadIdx.x;
    if (t < 512) {                               // W1c, rows permuted
        int p = t >> 3, i = t & 7;
        int ch = permch(p);
        float s1 = g1[ch] * rsqrtf(v1[ch] + EPSBN);
        float val;
        if (i < 4)      val = W1[i * 64 + ch] * s1;
        else if (i == 4) val = (b1[ch] - m1[ch]) * s1 + be1[ch];
        else             val = 0.f;
        wsh[WS_W1C + t] = (_Float16)val;
    } else if (t < 4608) {                       // W2T folded: rows permuted, cols natural
        int e = t - 512;
        int p = e >> 6, ch = e & 63;
        int chp = permch(p);
        float s2 = g2[chp] * rsqrtf(v2[chp] + EPSBN);
        wsh[t] = (_Float16)(W2[ch * 64 + chp] * s2);
    } else if (t < 12800) {                      // W3T: [o][ch] natural
        int e = t - 4608;
        int o = e >> 6, ch = e & 63;
        wsh[t] = (_Float16)W3[ch * 128 + o];
    } else if (t < 12864) {                      // c2 natural (indexing handled in mfma)
        int i = t - 12800;
        float s2 = g2[i] * rsqrtf(v2[i] + EPSBN);
        wsf[i] = (b2[i] - m2[i]) * s2 + be2[i];
    } else if (t < FOLD_THREADS) {               // b3
        int i = t - 12864;
        wsf[64 + i] = b3[i];
    }
}

// The verified per-chunk compute body (round-8/11 codegen, 60 VGPR), as a
// macro so both chunks are straight-line SSA (no arrays indexed by a loop
// carried variable -> no scratch demotion).
#define VFE_CHUNK(XV, NA, NB, VOXA)                                           \
  do {                                                                        \
    const bool actB1_ = ((NA) > 16);                                          \
    const bool actB3_ = ((NB) > 16);                                          \
    f16x8 a3[4][2] = {};                                                      \
    _Pragma("unroll")                                                         \
    for (int g = 0; g < 4; ++g) {                                             \
        if (g == 1 && !actB1_) continue;                                      \
        if (g == 3 && !actB3_) continue;                                      \
        f16x8 b = (f16x8)0;                                                   \
        if (q == 0) {                                                         \
            b[0] = (_Float16)XV[g].x; b[1] = (_Float16)XV[g].y;               \
            b[2] = (_Float16)XV[g].z; b[3] = (_Float16)XV[g].w;               \
            b[4] = (_Float16)1.0f;                                            \
        }                                                                     \
        f32x4 p1[4];                                                          \
        _Pragma("unroll")                                                     \
        for (int mt = 0; mt < 4; ++mt) {                                      \
            f32x4 z = {0.f, 0.f, 0.f, 0.f};                                   \
            p1[mt] = __builtin_amdgcn_mfma_f32_16x16x32_f16(a1[mt], b, z, 0, 0, 0); \
        }                                                                     \
        f16x8 b20, b21;                                                       \
        _Pragma("unroll")                                                     \
        for (int r = 0; r < 4; ++r) {                                         \
            b20[r]     = (_Float16)fmaxf(p1[0][r], 0.f);                      \
            b20[4 + r] = (_Float16)fmaxf(p1[2][r], 0.f);                      \
            b21[r]     = (_Float16)fmaxf(p1[1][r], 0.f);                      \
            b21[4 + r] = (_Float16)fmaxf(p1[3][r], 0.f);                      \
        }                                                                     \
        f32x4 p2[4];                                                          \
        _Pragma("unroll")                                                     \
        for (int mt = 0; mt < 4; ++mt) {                                      \
            f32x4 acc = c2v[mt];                                              \
            acc = __builtin_amdgcn_mfma_f32_16x16x32_f16(a2[mt][0], b20, acc, 0, 0, 0); \
            acc = __builtin_amdgcn_mfma_f32_16x16x32_f16(a2[mt][1], b21, acc, 0, 0, 0); \
            p2[mt] = acc;                                                     \
        }                                                                     \
        _Pragma("unroll")                                                     \
        for (int r = 0; r < 4; ++r) {                                         \
            a3[g][0][r]     = (_Float16)fmaxf(p2[0][r], 0.f);                 \
            a3[g][0][4 + r] = (_Float16)fmaxf(p2[2][r], 0.f);                 \
            a3[g][1][r]     = (_Float16)fmaxf(p2[1][r], 0.f);                 \
            a3[g][1][4 + r] = (_Float16)fmaxf(p2[3][r], 0.f);                 \
        }                                                                     \
    }                                                                         \
    f32x4 macc4[4];                                                           \
    _Pragma("unroll")                                                         \
    for (int g = 0; g < 4; ++g) {                                             \
        const int n_ = (g < 2) ? (NA) : (NB);                                 \
        const int slotbase_ = (g & 1) * 16 + q * 4;                           \
        _Pragma("unroll")                                                     \
        for (int r = 0; r < 4; ++r)                                           \
            macc4[g][r] = (slotbase_ + r < n_) ? 0.f : -INFINITY;             \
    }                                                                         \
    float vmA[8], vmB[8];                                                     \
    _Pragma("unroll")                                                         \
    for (int nt = 0; nt < 8; ++nt) { vmA[nt] = -INFINITY; vmB[nt] = -INFINITY; } \
    _Pragma("unroll")                                                         \
    for (int nt = 0; nt < 8; ++nt) {                                          \
        const int o_ = nt * 16 + m16;                                         \
        f16x8 b30 = *(const f16x8*)&sW3[o_ * 64 + ((q    ) ^ (m16 & 7)) * 8]; \
        f16x8 b31 = *(const f16x8*)&sW3[o_ * 64 + ((4 + q) ^ (m16 & 7)) * 8]; \
        _Pragma("unroll")                                                     \
        for (int g = 0; g < 4; ++g) {                                         \
            if (g == 1 && !actB1_) continue;                                  \
            if (g == 3 && !actB3_) continue;                                  \
            f32x4 acc = macc4[g];                                             \
            acc = __builtin_amdgcn_mfma_f32_16x16x32_f16(a3[g][0], b30, acc, 0, 0, 0); \
            acc = __builtin_amdgcn_mfma_f32_16x16x32_f16(a3[g][1], b31, acc, 0, 0, 0); \
            float m0 = fmaxf(fmaxf(acc[0], acc[1]), fmaxf(acc[2], acc[3]));   \
            if (g < 2) vmA[nt] = fmaxf(vmA[nt], m0);                          \
            else       vmB[nt] = fmaxf(vmB[nt], m0);                          \
        }                                                                     \
    }                                                                         \
    _Pragma("unroll")                                                         \
    for (int nt = 0; nt < 8; ++nt) {                                          \
        float t0 = vmA[nt];                                                   \
        t0 = fmaxf(t0, __shfl_xor(t0, 16));                                   \
        t0 = fmaxf(t0, __shfl_xor(t0, 32));                                   \
        float t1 = vmB[nt];                                                   \
        t1 = fmaxf(t1, __shfl_xor(t1, 16));                                   \
        t1 = fmaxf(t1, __shfl_xor(t1, 32));                                   \
        if (q == 0) out[(size_t)((VOXA) + 0) * ODIM + nt * 16 + m16] = t0 + b3r[nt]; \
        if (q == 1) out[(size_t)((VOXA) + 1) * ODIM + nt * 16 + m16] = t1 + b3r[nt]; \
    }                                                                         \
  } while (0)

// launch_bounds(256,3): cap 170 >> expected ~90 live VGPRs (spill-brittle
// codegen needs wide margin: caps 85/128 both misbehaved, 170 verified).
__global__ __launch_bounds__(256, 3) void vfe_mfma(
    const float* __restrict__ vf, const int* __restrict__ vnp,
    const _Float16* __restrict__ wsh, const float* __restrict__ wsf,
    float* __restrict__ out)
{
    // Block-shared W3 tile: [o][ch] stride 64, XOR-swizzled by 16B granule so
    // phase-3 reads (o = nt*16+m16 per lane) are 2-way (free) without padding.
    __shared__ __align__(16) _Float16 sW3[ODIM * HDIM];    // 16384 B

    const int tid  = threadIdx.x;
    const int wave = tid >> 6;
    const int lane = tid & 63;
    const int q    = lane >> 4;
    const int m16  = lane & 15;

    // Each block: 512 points = 16 voxels; each wave: 2 chunks of 64 points.
    const int base0 = blockIdx.x * 512 + wave * 64;
    const int base1 = base0 + 256;
    const int voxA0 = base0 >> 5;
    const int voxA1 = base1 >> 5;

    // ---- stage W3 into LDS (granule-swizzled), all 256 threads, once ----
#pragma unroll
    for (int i = 0; i < 4; ++i) {
        int G = tid + 256 * i;                   // granule id, 0..1023
        int o = G >> 3, gl = G & 7;              // row, logical 16B granule
        int ph = gl ^ (o & 7);                   // physical granule (XOR swizzle)
        f16x8 v = *(const f16x8*)&wsh[WS_W3T + o * 64 + gl * 8];
        *(f16x8*)&sW3[o * 64 + ph * 8] = v;
    }

    // ---- all point/count loads issued up-front (fly during staging+compute) ----
    const int nA0 = vnp[voxA0];
    const int nB0 = vnp[voxA0 + 1];
    const int nA1 = vnp[voxA1];
    const int nB1 = vnp[voxA1 + 1];

    float4 xv0[4], xv1[4];
#pragma unroll
    for (int g = 0; g < 4; ++g)
        if (q == 0) {
            xv0[g] = *(const float4*)(vf + ((size_t)base0 + g * 16 + m16) * 4);
            xv1[g] = *(const float4*)(vf + ((size_t)base1 + g * 16 + m16) * 4);
        }

    // ---- weight preloads (amortized over both chunks) ----
    f16x8 a1[4];
#pragma unroll
    for (int mt = 0; mt < 4; ++mt) {
        f16x8 t = *(const f16x8*)&wsh[WS_W1C + (m16 + 16 * mt) * 8];
        a1[mt] = (q == 0) ? t : (f16x8)0;      // k = q*8+j; only k<8 carries data
    }
    f16x8 a2[4][2];
#pragma unroll
    for (int mt = 0; mt < 4; ++mt)
#pragma unroll
        for (int kk = 0; kk < 2; ++kk)
            a2[mt][kk] = *(const f16x8*)&wsh[WS_W2T + (m16 + 16 * mt) * 64 + kk * 32 + q * 8];
    // c2 init must follow the permuted D2 rows: acc[mt][r] is out-channel
    // 32*(mt&1) + 8q + 4*(mt>>1) + r  (contiguous in r -> vector load).
    f32x4 c2v[4];
#pragma unroll
    for (int mt = 0; mt < 4; ++mt)
        c2v[mt] = *(const f32x4*)(wsf + (mt & 1) * 32 + q * 8 + (mt >> 1) * 4);
    float b3r[8];
#pragma unroll
    for (int nt = 0; nt < 8; ++nt) b3r[nt] = wsf[64 + nt * 16 + m16];

    __syncthreads();                             // W3 tile ready (only barrier)

    VFE_CHUNK(xv0, nA0, nB0, voxA0);
    VFE_CHUNK(xv1, nA1, nB1, voxA1);
}

extern "C" void kernel_launch(void* const* d_in, const int* in_sizes, int n_in,
                              void* d_out, int out_size, void* d_ws, size_t ws_size,
                              hipStream_t stream) {
    const float* vf  = (const float*)d_in[0];
    const int*   vnp = (const int*)d_in[1];
    const float* W1  = (const float*)d_in[2];
    const float* b1  = (const float*)d_in[3];
    const float* g1  = (const float*)d_in[4];
    const float* be1 = (const float*)d_in[5];
    const float* m1  = (const float*)d_in[6];
    const float* v1  = (const float*)d_in[7];
    const float* W2  = (const float*)d_in[8];
    const float* b2  = (const float*)d_in[9];
    const float* g2  = (const float*)d_in[10];
    const float* be2 = (const float*)d_in[11];
    const float* m2  = (const float*)d_in[12];
    const float* v2  = (const float*)d_in[13];
    const float* W3  = (const float*)d_in[14];
    const float* b3  = (const float*)d_in[15];
    float* out = (float*)d_out;

    _Float16* wsh = (_Float16*)d_ws;
    float*    wsf = (float*)((char*)d_ws + WS_F32_BYTE);

    vfe_fold<<<(FOLD_THREADS + 255) / 256, 256, 0, stream>>>(
        W1, b1, g1, be1, m1, v1, W2, b2, g2, be2, m2, v2, W3, b3, wsh, wsf);

    const int blocks = (NVOX * PPTS) / 512;   // 3125
    vfe_mfma<<<blocks, 256, 0, stream>>>(vf, vnp, wsh, wsf, out);
}